// Round 6
// baseline (282.010 us; speedup 1.0000x reference)
//
#include <hip/hip_runtime.h>
#include <math.h>

// ---------------------------------------------------------------------------
// PatchEmbedding: gather 9x9x3 patches from frames, x@W1+b1 -> GELU -> @W2+b2
// B=4, T=16, C=3, H=W=256, N=8192, patch_dim=243, EMBED=768
//
// R5 post-mortem: 128x256 single-buf == R3 (230.5 vs 228.7, noise) despite
// 3x lower LDS-read ratio => gemm2 NOT LDS-pipe bound. gemm2 ~53us: ~30us
// HBM-busy (186MB incl ~29MB excess Hbuf L2-eviction misses from the 96MB
// C-write stream), 18.6us MFMA. Controllable budget ~110-125us of the 228
// (rest = harness fill + gaps).
//
// R6: R3-exact GEMM structure (proven best anchor) + two isolated levers:
//   - NT stores on C in both GEMMs (keep L2 for Hbuf/W re-reads; R4's NT was
//     confounded by BK=32 — this isolates it).
//   - fuse w1T/w2T/gather into ONE k_prep kernel (blockIdx-partitioned;
//     removes 2 launch gaps, transposes run concurrent with gather).
// K-order trick unchanged: X and W1T use permuted k' = c*81 + i*9 + j.
// r4 lesson (prev session): no bucket-sorting the gather.
// ---------------------------------------------------------------------------

typedef __attribute__((ext_vector_type(8))) short short8;
typedef __attribute__((ext_vector_type(4))) float floatx4;

#define M_ROWS 32768      // B*N = 4*8192
#define KPAD   256        // patch_dim 243 padded to 256
#define EMB    768

typedef __attribute__((address_space(1))) const void g_void;
typedef __attribute__((address_space(3))) void l_void;

__device__ __forceinline__ unsigned short f2bf(float f) {
    union { float f; unsigned int i; } w;
    w.f = f;
    unsigned int x = w.i;
    x += 0x7fffu + ((x >> 16) & 1u);   // round-to-nearest-even
    return (unsigned short)(x >> 16);
}

// tanh-form GELU: max abs deviation from exact erf-GELU < 1e-3.
__device__ __forceinline__ float gelu_f(float x) {
    float x3 = x * x * x;
    float y  = 1.5957691216f * (x + 0.044715f * x3);   // 2*sqrt(2/pi)*(...)
    float e  = __expf(y);                               // e^{2z}
    float th = 1.0f - 2.0f / (e + 1.0f);                // tanh(z)
    return 0.5f * x * (1.0f + th);
}

// ---- fused prep: gather + W1 transpose + W2 transpose ---------------------
// grid 9536 x 256thr, partitioned:
//   [0,    8192) : gather patches -> X (4 rows/block, 1 wave/row)
//   [8192, 8960) : W1 (243x768 f32) -> W1T (768x256 bf16, permuted k')
//   [8960, 9536) : W2 (768x768 f32) -> W2T (768x768 bf16), 32x32 LDS tiles
__global__ void k_prep(const float* __restrict__ frames,
                       const float* __restrict__ coords,
                       const int* __restrict__ t_src,
                       const float* __restrict__ W1,
                       const float* __restrict__ W2,
                       unsigned short* __restrict__ X,
                       unsigned short* __restrict__ W1T,
                       unsigned short* __restrict__ W2T) {
    __shared__ float tile[32][33];   // used only by the w2 branch (4.3 KB)
    const int bid = blockIdx.x;

    if (bid < 8192) {
        // ---- gather (channel-major order k') ----
        int row  = bid * 4 + (threadIdx.x >> 6);   // 0..32767
        int lane = threadIdx.x & 63;
        int b = row >> 13;

        float cu = coords[row * 2 + 0];
        float cv = coords[row * 2 + 1];
        int u = (int)(cu * 255.0f);   // exact fp32 math, matches reference
        int v = (int)(cv * 255.0f);
        int t = t_src[row];

        const float* fb = frames + (size_t)(b * 16 + t) * (3 * 256 * 256);
        unsigned short* xr = X + (size_t)row * KPAD;

#pragma unroll
        for (int it = 0; it < 4; ++it) {
            int kp = lane + it * 64;            // permuted index c*81 + i*9 + j
            unsigned short val = 0;
            if (kp < 243) {
                int c = kp / 81;
                int r = kp - c * 81;
                int i = r / 9;
                int j = r - i * 9;
                int y = v + i - 4; y = (y < 0) ? 0 : (y > 255 ? 255 : y);
                int x = u + j - 4; x = (x < 0) ? 0 : (x > 255 ? 255 : x);
                val = f2bf(fb[(size_t)c * 65536 + y * 256 + x]);
            }
            xr[kp] = val;
        }
    } else if (bid < 8192 + 768) {
        // ---- W1 -> W1T (zero-pad to 256, permuted k') ----
        int idx = (bid - 8192) * 256 + threadIdx.x;   // 768*256 total
        int n  = idx >> 8;        // 0..767
        int kp = idx & 255;       // permuted k': c*81 + i*9 + j
        unsigned short v = 0;
        if (kp < 243) {
            int c = kp / 81;
            int r = kp - c * 81;
            int i = r / 9;
            int j = r - i * 9;
            int e = i * 27 + j * 3 + c;   // reference order
            v = f2bf(W1[e * EMB + n]);
        }
        W1T[idx] = v;
    } else {
        // ---- W2 -> W2T (LDS-tiled 32x32 transpose) ----
        int tb = bid - 8960;                 // 0..575 = 24x24
        int tx = threadIdx.x & 31, ty = threadIdx.x >> 5;   // 32 x 8
        int k0 = (tb / 24) * 32, n0 = (tb % 24) * 32;
#pragma unroll
        for (int i = 0; i < 4; ++i)
            tile[ty + i * 8][tx] = W2[(size_t)(k0 + ty + i * 8) * EMB + n0 + tx];
        __syncthreads();
#pragma unroll
        for (int i = 0; i < 4; ++i)
            W2T[(size_t)(n0 + ty + i * 8) * EMB + k0 + tx] = f2bf(tile[tx][ty + i * 8]);
    }
}

// ---- MFMA GEMM body (R3-exact structure + NT C-stores) --------------------
// 128x128 tile / 8 waves (each 64x32 via 4x2 16x16x32). BK=64, double-buffered
// LDS (64KB), global_load_lds width=16 issued right after the single
// per-iteration barrier. XOR swizzle: logical 16B slot s of row r at physical
// slot s^(r&7); gll dest linear, source pre-swizzled.
// Grid FLAT 1536 = 256 M-tiles x 6 N-tiles, XCD-chunk swizzled, y-fastest.
template <int K, bool GELU_, bool OUT_F32>
static __device__ __forceinline__
void gemm_body(const unsigned short* __restrict__ A,
               const unsigned short* __restrict__ BT,
               const float* __restrict__ bias,
               void* __restrict__ Cv) {
    __shared__ unsigned short As[2][128 * 64];   // 16 KB each
    __shared__ unsigned short Bs[2][128 * 64];   // total LDS = 64 KB

    const int tid  = threadIdx.x;
    const int wave = tid >> 6;      // 0..7
    const int lane = tid & 63;
    const int wr = wave >> 2;       // 0..1 : M half (64 rows)
    const int wc = wave & 3;        // 0..3 : N quarter (32 cols)
    const int lm = lane & 15;
    const int lq = lane >> 4;

    // XCD-chunked bijective swizzle (nwg=1536, 192/XCD), y-fastest so the 6
    // blocks sharing one A-panel are consecutive logical tiles -> same XCD L2.
    const int bid = blockIdx.x;
    const int swz = (bid & 7) * 192 + (bid >> 3);
    const int by  = swz % 6;
    const int bx  = swz / 6;
    const int m0 = bx * 128;
    const int n0 = by * 128;

    floatx4 acc[4][2];
#pragma unroll
    for (int i = 0; i < 4; ++i)
#pragma unroll
        for (int j = 0; j < 2; ++j)
            acc[i][j] = (floatx4){0.f, 0.f, 0.f, 0.f};

    const unsigned short* Ag = A  + (size_t)m0 * K;
    const unsigned short* Bg = BT + (size_t)n0 * K;

    // staging: chunk c = i*8 + wave covers rows c*8..c*8+7 (8 rows x 64 cols).
    // lane l -> row c*8 + (l>>3), physical 16B slot l&7; source pre-swizzled.
    const int rl    = lane >> 3;
    const int pl    = lane & 7;
    const int lslot = pl ^ rl;           // (r&7) == rl for all chunks
    const int c0 = wave;                 // i = 0
    const int c1 = 8 + wave;             // i = 1
    const size_t o0 = (size_t)(c0 * 8 + rl) * K + (lslot << 3);
    const size_t o1 = (size_t)(c1 * 8 + rl) * K + (lslot << 3);

    // prologue: issue tile 0 into buffer 0
    __builtin_amdgcn_global_load_lds((g_void*)(Ag + o0), (l_void*)(&As[0][c0 * 512]), 16, 0, 0);
    __builtin_amdgcn_global_load_lds((g_void*)(Ag + o1), (l_void*)(&As[0][c1 * 512]), 16, 0, 0);
    __builtin_amdgcn_global_load_lds((g_void*)(Bg + o0), (l_void*)(&Bs[0][c0 * 512]), 16, 0, 0);
    __builtin_amdgcn_global_load_lds((g_void*)(Bg + o1), (l_void*)(&Bs[0][c1 * 512]), 16, 0, 0);

    int buf = 0;
    for (int k0 = 0; k0 < K; k0 += 64) {
        __syncthreads();   // drains gll for tile(k0), closes reads of buf^1

        if (k0 + 64 < K) {
            __builtin_amdgcn_global_load_lds((g_void*)(Ag + o0 + k0 + 64),
                                             (l_void*)(&As[buf ^ 1][c0 * 512]), 16, 0, 0);
            __builtin_amdgcn_global_load_lds((g_void*)(Ag + o1 + k0 + 64),
                                             (l_void*)(&As[buf ^ 1][c1 * 512]), 16, 0, 0);
            __builtin_amdgcn_global_load_lds((g_void*)(Bg + o0 + k0 + 64),
                                             (l_void*)(&Bs[buf ^ 1][c0 * 512]), 16, 0, 0);
            __builtin_amdgcn_global_load_lds((g_void*)(Bg + o1 + k0 + 64),
                                             (l_void*)(&Bs[buf ^ 1][c1 * 512]), 16, 0, 0);
        }

#pragma unroll
        for (int ks = 0; ks < 2; ++ks) {         // two K=32 steps per BK=64
            short8 af[4], bfr[2];
#pragma unroll
            for (int mi = 0; mi < 4; ++mi) {
                int row = wr * 64 + mi * 16 + lm;
                int ps  = ((ks << 2) + lq) ^ (row & 7);
                af[mi] = *(const short8*)(&As[buf][row * 64 + (ps << 3)]);
            }
#pragma unroll
            for (int ni = 0; ni < 2; ++ni) {
                int row = wc * 32 + ni * 16 + lm;
                int ps  = ((ks << 2) + lq) ^ (row & 7);
                bfr[ni] = *(const short8*)(&Bs[buf][row * 64 + (ps << 3)]);
            }
#pragma unroll
            for (int mi = 0; mi < 4; ++mi)
#pragma unroll
                for (int ni = 0; ni < 2; ++ni)
                    acc[mi][ni] = __builtin_amdgcn_mfma_f32_16x16x32_bf16(
                        af[mi], bfr[ni], acc[mi][ni], 0, 0, 0);
        }
        buf ^= 1;
    }

    // epilogue: D[row][col], row = lq*4 + r, col = lm within each 16x16 tile.
    // NT stores: keep the 96MB C stream from evicting Hbuf/W panels in L2.
#pragma unroll
    for (int ni = 0; ni < 2; ++ni) {
        int col = n0 + wc * 32 + ni * 16 + lm;
        float bs = bias[col];
#pragma unroll
        for (int mi = 0; mi < 4; ++mi) {
            int rowb = m0 + wr * 64 + mi * 16 + lq * 4;
#pragma unroll
            for (int r = 0; r < 4; ++r) {
                float x = acc[mi][ni][r] + bs;
                if (GELU_)
                    x = gelu_f(x);
                size_t idx = (size_t)(rowb + r) * EMB + col;
                if (OUT_F32)
                    __builtin_nontemporal_store(x, &((float*)Cv)[idx]);
                else
                    __builtin_nontemporal_store(f2bf(x), &((unsigned short*)Cv)[idx]);
            }
        }
    }
}

// distinct names so rocprof shows each GEMM separately
__global__ __launch_bounds__(512, 4)
void k_gemm1(const unsigned short* __restrict__ A, const unsigned short* __restrict__ BT,
             const float* __restrict__ bias, unsigned short* __restrict__ C) {
    gemm_body<KPAD, true, false>(A, BT, bias, (void*)C);
}

__global__ __launch_bounds__(512, 4)
void k_gemm2(const unsigned short* __restrict__ A, const unsigned short* __restrict__ BT,
             const float* __restrict__ bias, float* __restrict__ C) {
    gemm_body<EMB, false, true>(A, BT, bias, (void*)C);
}

// ---------------------------------------------------------------------------
extern "C" void kernel_launch(void* const* d_in, const int* in_sizes, int n_in,
                              void* d_out, int out_size, void* d_ws, size_t ws_size,
                              hipStream_t stream) {
    const float* frames = (const float*)d_in[0];
    const float* coords = (const float*)d_in[1];
    const int*   t_src  = (const int*)d_in[2];
    const float* W1     = (const float*)d_in[3];
    const float* b1     = (const float*)d_in[4];
    const float* W2     = (const float*)d_in[5];
    const float* b2     = (const float*)d_in[6];
    float* out = (float*)d_out;

    char* ws = (char*)d_ws;
    // workspace layout:
    //   X    : 32768*256*2 = 16,777,216 B  (bf16, permuted k')
    //   Hbuf : 32768*768*2 = 50,331,648 B  (bf16)
    //   W1T  : 768*256*2   =    393,216 B  (bf16, permuted k')
    //   W2T  : 768*768*2   =  1,179,648 B  (bf16)
    unsigned short* X    = (unsigned short*)(ws);
    unsigned short* Hbuf = (unsigned short*)(ws + 16777216);
    unsigned short* W1T  = (unsigned short*)(ws + 16777216 + 50331648);
    unsigned short* W2T  = (unsigned short*)(ws + 16777216 + 50331648 + 393216);

    // fused prep: gather + both weight transposes in one dispatch
    k_prep<<<9536, 256, 0, stream>>>(frames, coords, t_src, W1, W2, X, W1T, W2T);

    // GEMM1: H = gelu(X @ W1 + b1)   (K = 256 padded), bf16 out
    k_gemm1<<<1536, 512, 0, stream>>>(X, W1T, b1, Hbuf);

    // GEMM2: out = H @ W2 + b2       (K = 768), fp32 out
    k_gemm2<<<1536, 512, 0, stream>>>(Hbuf, W2T, b2, out);
}

// Round 9
// 222.920 us; speedup vs baseline: 1.2651x; 1.2651x over previous
//
#include <hip/hip_runtime.h>
#include <math.h>

// ---------------------------------------------------------------------------
// PatchEmbedding: gather 9x9x3 patches from frames, x@W1+b1 -> GELU -> @W2+b2
// B=4, T=16, C=3, H=W=256, N=8192, patch_dim=243, EMBED=768
//
// R6 post-mortem: NT stores REFUTED — FETCH dropped 80->29.5MB as predicted
// (C-stream was evicting Hbuf from L2) but the NT write path is slow on
// gfx950: WRITE 102->131.5MB (partial-line, no L2 write-combining), BW
// 1.86TB/s, gemm2 58->88.6us. Net traffic fell, time rose => store-path
// latency, not traffic. Prep fusion ~neutral by arithmetic (NT explains the
// whole +53) — kept for fewer launch gaps.
//
// R7: R3-exact GEMM bodies (plain stores, the 228.7us measured anchor) +
// fused k_prep. Nothing else.
// R8/R9: identical re-submits — R7 and R8 benches both failed at container
// acquisition (no measurement). Source is near-identical to R6's clean run
// (only epilogue store insn differs), so kernel-induced failure is ruled out.
// K-order trick unchanged: X and W1T use permuted k' = c*81 + i*9 + j.
// r4 lesson (prev session): no bucket-sorting the gather.
// ---------------------------------------------------------------------------

typedef __attribute__((ext_vector_type(8))) short short8;
typedef __attribute__((ext_vector_type(4))) float floatx4;

#define M_ROWS 32768      // B*N = 4*8192
#define KPAD   256        // patch_dim 243 padded to 256
#define EMB    768

typedef __attribute__((address_space(1))) const void g_void;
typedef __attribute__((address_space(3))) void l_void;

__device__ __forceinline__ unsigned short f2bf(float f) {
    union { float f; unsigned int i; } w;
    w.f = f;
    unsigned int x = w.i;
    x += 0x7fffu + ((x >> 16) & 1u);   // round-to-nearest-even
    return (unsigned short)(x >> 16);
}

// tanh-form GELU: max abs deviation from exact erf-GELU < 1e-3.
__device__ __forceinline__ float gelu_f(float x) {
    float x3 = x * x * x;
    float y  = 1.5957691216f * (x + 0.044715f * x3);   // 2*sqrt(2/pi)*(...)
    float e  = __expf(y);                               // e^{2z}
    float th = 1.0f - 2.0f / (e + 1.0f);                // tanh(z)
    return 0.5f * x * (1.0f + th);
}

// ---- fused prep: gather + W1 transpose + W2 transpose ---------------------
// grid 9536 x 256thr, partitioned:
//   [0,    8192) : gather patches -> X (4 rows/block, 1 wave/row)
//   [8192, 8960) : W1 (243x768 f32) -> W1T (768x256 bf16, permuted k')
//   [8960, 9536) : W2 (768x768 f32) -> W2T (768x768 bf16), 32x32 LDS tiles
__global__ void k_prep(const float* __restrict__ frames,
                       const float* __restrict__ coords,
                       const int* __restrict__ t_src,
                       const float* __restrict__ W1,
                       const float* __restrict__ W2,
                       unsigned short* __restrict__ X,
                       unsigned short* __restrict__ W1T,
                       unsigned short* __restrict__ W2T) {
    __shared__ float tile[32][33];   // used only by the w2 branch (4.3 KB)
    const int bid = blockIdx.x;

    if (bid < 8192) {
        // ---- gather (channel-major order k') ----
        int row  = bid * 4 + (threadIdx.x >> 6);   // 0..32767
        int lane = threadIdx.x & 63;
        int b = row >> 13;

        float cu = coords[row * 2 + 0];
        float cv = coords[row * 2 + 1];
        int u = (int)(cu * 255.0f);   // exact fp32 math, matches reference
        int v = (int)(cv * 255.0f);
        int t = t_src[row];

        const float* fb = frames + (size_t)(b * 16 + t) * (3 * 256 * 256);
        unsigned short* xr = X + (size_t)row * KPAD;

#pragma unroll
        for (int it = 0; it < 4; ++it) {
            int kp = lane + it * 64;            // permuted index c*81 + i*9 + j
            unsigned short val = 0;
            if (kp < 243) {
                int c = kp / 81;
                int r = kp - c * 81;
                int i = r / 9;
                int j = r - i * 9;
                int y = v + i - 4; y = (y < 0) ? 0 : (y > 255 ? 255 : y);
                int x = u + j - 4; x = (x < 0) ? 0 : (x > 255 ? 255 : x);
                val = f2bf(fb[(size_t)c * 65536 + y * 256 + x]);
            }
            xr[kp] = val;
        }
    } else if (bid < 8192 + 768) {
        // ---- W1 -> W1T (zero-pad to 256, permuted k') ----
        int idx = (bid - 8192) * 256 + threadIdx.x;   // 768*256 total
        int n  = idx >> 8;        // 0..767
        int kp = idx & 255;       // permuted k': c*81 + i*9 + j
        unsigned short v = 0;
        if (kp < 243) {
            int c = kp / 81;
            int r = kp - c * 81;
            int i = r / 9;
            int j = r - i * 9;
            int e = i * 27 + j * 3 + c;   // reference order
            v = f2bf(W1[e * EMB + n]);
        }
        W1T[idx] = v;
    } else {
        // ---- W2 -> W2T (LDS-tiled 32x32 transpose) ----
        int tb = bid - 8960;                 // 0..575 = 24x24
        int tx = threadIdx.x & 31, ty = threadIdx.x >> 5;   // 32 x 8
        int k0 = (tb / 24) * 32, n0 = (tb % 24) * 32;
#pragma unroll
        for (int i = 0; i < 4; ++i)
            tile[ty + i * 8][tx] = W2[(size_t)(k0 + ty + i * 8) * EMB + n0 + tx];
        __syncthreads();
#pragma unroll
        for (int i = 0; i < 4; ++i)
            W2T[(size_t)(n0 + ty + i * 8) * EMB + k0 + tx] = f2bf(tile[tx][ty + i * 8]);
    }
}

// ---- MFMA GEMM body (R3-exact structure, plain stores) --------------------
// 128x128 tile / 8 waves (each 64x32 via 4x2 16x16x32). BK=64, double-buffered
// LDS (64KB), global_load_lds width=16 issued right after the single
// per-iteration barrier. XOR swizzle: logical 16B slot s of row r at physical
// slot s^(r&7); gll dest linear, source pre-swizzled.
// Grid FLAT 1536 = 256 M-tiles x 6 N-tiles, XCD-chunk swizzled, y-fastest.
template <int K, bool GELU_, bool OUT_F32>
static __device__ __forceinline__
void gemm_body(const unsigned short* __restrict__ A,
               const unsigned short* __restrict__ BT,
               const float* __restrict__ bias,
               void* __restrict__ Cv) {
    __shared__ unsigned short As[2][128 * 64];   // 16 KB each
    __shared__ unsigned short Bs[2][128 * 64];   // total LDS = 64 KB

    const int tid  = threadIdx.x;
    const int wave = tid >> 6;      // 0..7
    const int lane = tid & 63;
    const int wr = wave >> 2;       // 0..1 : M half (64 rows)
    const int wc = wave & 3;        // 0..3 : N quarter (32 cols)
    const int lm = lane & 15;
    const int lq = lane >> 4;

    // XCD-chunked bijective swizzle (nwg=1536, 192/XCD), y-fastest so the 6
    // blocks sharing one A-panel are consecutive logical tiles -> same XCD L2.
    const int bid = blockIdx.x;
    const int swz = (bid & 7) * 192 + (bid >> 3);
    const int by  = swz % 6;
    const int bx  = swz / 6;
    const int m0 = bx * 128;
    const int n0 = by * 128;

    floatx4 acc[4][2];
#pragma unroll
    for (int i = 0; i < 4; ++i)
#pragma unroll
        for (int j = 0; j < 2; ++j)
            acc[i][j] = (floatx4){0.f, 0.f, 0.f, 0.f};

    const unsigned short* Ag = A  + (size_t)m0 * K;
    const unsigned short* Bg = BT + (size_t)n0 * K;

    // staging: chunk c = i*8 + wave covers rows c*8..c*8+7 (8 rows x 64 cols).
    // lane l -> row c*8 + (l>>3), physical 16B slot l&7; source pre-swizzled.
    const int rl    = lane >> 3;
    const int pl    = lane & 7;
    const int lslot = pl ^ rl;           // (r&7) == rl for all chunks
    const int c0 = wave;                 // i = 0
    const int c1 = 8 + wave;             // i = 1
    const size_t o0 = (size_t)(c0 * 8 + rl) * K + (lslot << 3);
    const size_t o1 = (size_t)(c1 * 8 + rl) * K + (lslot << 3);

    // prologue: issue tile 0 into buffer 0
    __builtin_amdgcn_global_load_lds((g_void*)(Ag + o0), (l_void*)(&As[0][c0 * 512]), 16, 0, 0);
    __builtin_amdgcn_global_load_lds((g_void*)(Ag + o1), (l_void*)(&As[0][c1 * 512]), 16, 0, 0);
    __builtin_amdgcn_global_load_lds((g_void*)(Bg + o0), (l_void*)(&Bs[0][c0 * 512]), 16, 0, 0);
    __builtin_amdgcn_global_load_lds((g_void*)(Bg + o1), (l_void*)(&Bs[0][c1 * 512]), 16, 0, 0);

    int buf = 0;
    for (int k0 = 0; k0 < K; k0 += 64) {
        __syncthreads();   // drains gll for tile(k0), closes reads of buf^1

        if (k0 + 64 < K) {
            __builtin_amdgcn_global_load_lds((g_void*)(Ag + o0 + k0 + 64),
                                             (l_void*)(&As[buf ^ 1][c0 * 512]), 16, 0, 0);
            __builtin_amdgcn_global_load_lds((g_void*)(Ag + o1 + k0 + 64),
                                             (l_void*)(&As[buf ^ 1][c1 * 512]), 16, 0, 0);
            __builtin_amdgcn_global_load_lds((g_void*)(Bg + o0 + k0 + 64),
                                             (l_void*)(&Bs[buf ^ 1][c0 * 512]), 16, 0, 0);
            __builtin_amdgcn_global_load_lds((g_void*)(Bg + o1 + k0 + 64),
                                             (l_void*)(&Bs[buf ^ 1][c1 * 512]), 16, 0, 0);
        }

#pragma unroll
        for (int ks = 0; ks < 2; ++ks) {         // two K=32 steps per BK=64
            short8 af[4], bfr[2];
#pragma unroll
            for (int mi = 0; mi < 4; ++mi) {
                int row = wr * 64 + mi * 16 + lm;
                int ps  = ((ks << 2) + lq) ^ (row & 7);
                af[mi] = *(const short8*)(&As[buf][row * 64 + (ps << 3)]);
            }
#pragma unroll
            for (int ni = 0; ni < 2; ++ni) {
                int row = wc * 32 + ni * 16 + lm;
                int ps  = ((ks << 2) + lq) ^ (row & 7);
                bfr[ni] = *(const short8*)(&Bs[buf][row * 64 + (ps << 3)]);
            }
#pragma unroll
            for (int mi = 0; mi < 4; ++mi)
#pragma unroll
                for (int ni = 0; ni < 2; ++ni)
                    acc[mi][ni] = __builtin_amdgcn_mfma_f32_16x16x32_bf16(
                        af[mi], bfr[ni], acc[mi][ni], 0, 0, 0);
        }
        buf ^= 1;
    }

    // epilogue: D[row][col], row = lq*4 + r, col = lm within each 16x16 tile
#pragma unroll
    for (int ni = 0; ni < 2; ++ni) {
        int col = n0 + wc * 32 + ni * 16 + lm;
        float bs = bias[col];
#pragma unroll
        for (int mi = 0; mi < 4; ++mi) {
            int rowb = m0 + wr * 64 + mi * 16 + lq * 4;
#pragma unroll
            for (int r = 0; r < 4; ++r) {
                float x = acc[mi][ni][r] + bs;
                if (GELU_)
                    x = gelu_f(x);
                size_t idx = (size_t)(rowb + r) * EMB + col;
                if (OUT_F32)
                    ((float*)Cv)[idx] = x;
                else
                    ((unsigned short*)Cv)[idx] = f2bf(x);
            }
        }
    }
}

// distinct names so rocprof shows each GEMM separately
__global__ __launch_bounds__(512, 4)
void k_gemm1(const unsigned short* __restrict__ A, const unsigned short* __restrict__ BT,
             const float* __restrict__ bias, unsigned short* __restrict__ C) {
    gemm_body<KPAD, true, false>(A, BT, bias, (void*)C);
}

__global__ __launch_bounds__(512, 4)
void k_gemm2(const unsigned short* __restrict__ A, const unsigned short* __restrict__ BT,
             const float* __restrict__ bias, float* __restrict__ C) {
    gemm_body<EMB, false, true>(A, BT, bias, (void*)C);
}

// ---------------------------------------------------------------------------
extern "C" void kernel_launch(void* const* d_in, const int* in_sizes, int n_in,
                              void* d_out, int out_size, void* d_ws, size_t ws_size,
                              hipStream_t stream) {
    const float* frames = (const float*)d_in[0];
    const float* coords = (const float*)d_in[1];
    const int*   t_src  = (const int*)d_in[2];
    const float* W1     = (const float*)d_in[3];
    const float* b1     = (const float*)d_in[4];
    const float* W2     = (const float*)d_in[5];
    const float* b2     = (const float*)d_in[6];
    float* out = (float*)d_out;

    char* ws = (char*)d_ws;
    // workspace layout:
    //   X    : 32768*256*2 = 16,777,216 B  (bf16, permuted k')
    //   Hbuf : 32768*768*2 = 50,331,648 B  (bf16)
    //   W1T  : 768*256*2   =    393,216 B  (bf16, permuted k')
    //   W2T  : 768*768*2   =  1,179,648 B  (bf16)
    unsigned short* X    = (unsigned short*)(ws);
    unsigned short* Hbuf = (unsigned short*)(ws + 16777216);
    unsigned short* W1T  = (unsigned short*)(ws + 16777216 + 50331648);
    unsigned short* W2T  = (unsigned short*)(ws + 16777216 + 50331648 + 393216);

    // fused prep: gather + both weight transposes in one dispatch
    k_prep<<<9536, 256, 0, stream>>>(frames, coords, t_src, W1, W2, X, W1T, W2T);

    // GEMM1: H = gelu(X @ W1 + b1)   (K = 256 padded), bf16 out
    k_gemm1<<<1536, 512, 0, stream>>>(X, W1T, b1, Hbuf);

    // GEMM2: out = H @ W2 + b2       (K = 768), fp32 out
    k_gemm2<<<1536, 512, 0, stream>>>(Hbuf, W2T, b2, out);
}